// Round 9
// baseline (408.083 us; speedup 1.0000x reference)
//
#include <hip/hip_runtime.h>
#include <stdint.h>

// Problem: B=2, S=2048, D=1024, H=16, dh=64
// Inputs fp32, OUTPUT fp32. Internals bf16 (threshold has bf16 floor).
#define SEQ    2048
#define DMODEL 1024

typedef __bf16 bf16x8 __attribute__((ext_vector_type(8)));
typedef float  f32x4  __attribute__((ext_vector_type(4)));

typedef __attribute__((address_space(1))) const void CGV;  // global
typedef __attribute__((address_space(3))) void LDSV;       // LDS

__device__ __forceinline__ void load_lds16(const void* g, void* l) {
    __builtin_amdgcn_global_load_lds((CGV*)g, (LDSV*)l, 16, 0, 0);
}

// ---------------------------------------------------------------------------
// Transpose+convert: in f32 [R][C] -> out bf16 [C][R].  grid (C/32, R/32), 256
// ---------------------------------------------------------------------------
__global__ __launch_bounds__(256)
void transpose_f32_to_bf16(const float* __restrict__ in, __bf16* __restrict__ out,
                           int R, int C)
{
    __shared__ float tile[32][33];
    const int t  = threadIdx.x;
    const int tx = t & 31, ty = t >> 5;
    const int c0 = blockIdx.x * 32;
    const int r0 = blockIdx.y * 32;
#pragma unroll
    for (int i = 0; i < 4; ++i)
        tile[ty + i * 8][tx] = in[(size_t)(r0 + ty + i * 8) * C + c0 + tx];
    __syncthreads();
#pragma unroll
    for (int i = 0; i < 4; ++i)
        out[(size_t)(c0 + ty + i * 8) * R + r0 + tx] = (__bf16)tile[tx][ty + i * 8];
}

// ---------------------------------------------------------------------------
// V transpose (bf16): in [32][2048][64] -> out [32][64][2048]
// grid (SEQ/32, 64/32, 32), 256 thr   (R6-proven; keeps GEMM1 epilogue coalesced)
// ---------------------------------------------------------------------------
__global__ __launch_bounds__(256)
void transpose_v(const __bf16* __restrict__ in, __bf16* __restrict__ out)
{
    __shared__ __bf16 tile[32][34];
    const int t  = threadIdx.x;
    const int tx = t & 31, ty = t >> 5;
    const int s0 = blockIdx.x * 32;
    const int d0 = blockIdx.y * 32;
    const int bh = blockIdx.z;
    const __bf16* ip = in  + (size_t)bh * SEQ * 64;
    __bf16*       op = out + (size_t)bh * 64 * SEQ;
#pragma unroll
    for (int i = 0; i < 4; ++i)
        tile[ty + i * 8][tx] = ip[(size_t)(s0 + ty + i * 8) * 64 + d0 + tx];
    __syncthreads();
#pragma unroll
    for (int i = 0; i < 4; ++i)
        op[(size_t)(d0 + ty + i * 8) * SEQ + s0 + tx] = tile[tx][ty + i * 8];
}

// ---------------------------------------------------------------------------
// GEMM (m97 structure): C[M x N] = A[M x K] @ Bt[N x K]^T + bias[N]
// mode 0: scatter bf16 Q/K/V row-major [B,H,S,dh];  mode 1: fp32 row-major
// (R6-proven version)
// ---------------------------------------------------------------------------
template<bool A_IS_F32>
__global__ __launch_bounds__(256)
void gemm_kernel(const void* __restrict__ Av, const __bf16* __restrict__ Bt,
                 const float* __restrict__ bias,
                 __bf16* __restrict__ Cq, __bf16* __restrict__ Ck,
                 __bf16* __restrict__ Cv, float* __restrict__ Cplain,
                 int K, int N, int mode)
{
    __shared__ __attribute__((aligned(16))) __bf16 As[128][32];
    __shared__ __attribute__((aligned(16))) __bf16 Bs[128][32];

    const int t    = threadIdx.x;
    const int wave = __builtin_amdgcn_readfirstlane(t >> 6);
    const int lane = t & 63;
    const int l15  = lane & 15;
    const int quad = lane >> 4;
    const int wm   = (wave >> 1) * 64;
    const int wn   = (wave & 1) * 64;
    const int m0   = blockIdx.y * 128;
    const int n0   = blockIdx.x * 128;

    const int arow  = lane >> 2;
    const int akoff = (lane & 3) * 8;

    f32x4 acc[4][4] = {};

    for (int k0 = 0; k0 < K; k0 += 32) {
        __syncthreads();
        if (A_IS_F32) {
            const float* A = (const float*)Av;
            int row = t >> 1, kk = (t & 1) * 16;
            const float* srcp = A + (size_t)(m0 + row) * K + k0 + kk;
            float4 v0 = *(const float4*)(srcp);
            float4 v1 = *(const float4*)(srcp + 4);
            float4 v2 = *(const float4*)(srcp + 8);
            float4 v3 = *(const float4*)(srcp + 12);
            __bf16 tmp[16] = {
                (__bf16)v0.x, (__bf16)v0.y, (__bf16)v0.z, (__bf16)v0.w,
                (__bf16)v1.x, (__bf16)v1.y, (__bf16)v1.z, (__bf16)v1.w,
                (__bf16)v2.x, (__bf16)v2.y, (__bf16)v2.z, (__bf16)v2.w,
                (__bf16)v3.x, (__bf16)v3.y, (__bf16)v3.z, (__bf16)v3.w };
            *(uint4*)(&As[row][kk])     = *(uint4*)(tmp);
            *(uint4*)(&As[row][kk + 8]) = *(uint4*)(tmp + 8);
        } else {
            const __bf16* A = (const __bf16*)Av;
#pragma unroll
            for (int p = 0; p < 2; ++p) {
                int slab = (wave * 2 + p) * 16;
                const __bf16* g = A + (size_t)(m0 + slab + arow) * K + k0 + akoff;
                load_lds16(g, &As[slab][0]);
            }
        }
#pragma unroll
        for (int p = 0; p < 2; ++p) {
            int slab = (wave * 2 + p) * 16;
            const __bf16* g = Bt + (size_t)(n0 + slab + arow) * K + k0 + akoff;
            load_lds16(g, &Bs[slab][0]);
        }
        __syncthreads();

        bf16x8 af[4], bfr[4];
#pragma unroll
        for (int mi = 0; mi < 4; ++mi)
            af[mi] = *(const bf16x8*)(&As[wm + mi * 16 + l15][quad * 8]);
#pragma unroll
        for (int ni = 0; ni < 4; ++ni)
            bfr[ni] = *(const bf16x8*)(&Bs[wn + ni * 16 + l15][quad * 8]);
#pragma unroll
        for (int mi = 0; mi < 4; ++mi)
#pragma unroll
            for (int ni = 0; ni < 4; ++ni)
                acc[mi][ni] = __builtin_amdgcn_mfma_f32_16x16x32_bf16(
                    af[mi], bfr[ni], acc[mi][ni], 0, 0, 0);
    }

#pragma unroll
    for (int mi = 0; mi < 4; ++mi) {
        int rowb = m0 + wm + mi * 16 + quad * 4;
#pragma unroll
        for (int ni = 0; ni < 4; ++ni) {
            int col = n0 + wn + ni * 16 + l15;
            float bia = bias[col];
#pragma unroll
            for (int r = 0; r < 4; ++r) {
                float v = acc[mi][ni][r] + bia;
                int rr = rowb + r;
                if (mode == 0) {
                    int b = rr >> 11;
                    int s = rr & 2047;
                    int part = col >> 10;
                    int rem  = col & 1023;
                    int h = rem >> 6;
                    int d = rem & 63;
                    __bf16* dst = (part == 0) ? Cq : (part == 1) ? Ck : Cv;
                    dst[(((size_t)(b * 16 + h)) * SEQ + s) * 64 + d] = (__bf16)v;
                } else {
                    Cplain[(size_t)rr * N + col] = v;
                }
            }
        }
    }
}

// ---------------------------------------------------------------------------
// MFMA flash attention, single-barrier software pipeline (S^T formulation):
//  - ONE __syncthreads per iter; every global load issued right AFTER a
//    barrier and consumed right BEFORE the next -> no vmcnt(0) drain stall.
//  - V: regs (prefetched 1 iter ahead) -> LDS double buffer, commit at top.
//  - mask: 4x float4 regs, prefetched 1 iter ahead.
//  - K: regs prefetched late in iter kt; QK(kt+1) computed at END of iter kt.
// grid (B*H=32, S/64=32); 4 waves x 16 q rows.
// ---------------------------------------------------------------------------
__global__ __launch_bounds__(256, 4)
void attn_kernel(const __bf16* __restrict__ Q, const __bf16* __restrict__ Kb,
                 const __bf16* __restrict__ Vtg, const float* __restrict__ mask,
                 __bf16* __restrict__ Out)
{
    __shared__ __attribute__((aligned(16))) __bf16 Vt[2][64][72];  // dbuf [d][key]
    __shared__ __attribute__((aligned(16))) __bf16 Ps[4][16][72];  // wave P [q][key]

    const int t    = threadIdx.x;
    const int wave = t >> 6;
    const int lane = t & 63;
    const int l15  = lane & 15;
    const int quad = lane >> 4;
    const int bh   = blockIdx.x;
    const int b    = bh >> 4;
    const int h    = bh & 15;
    const int bq0  = blockIdx.y * 64;
    const int q0   = bq0 + wave * 16;

    const __bf16* Qp  = Q   + (size_t)bh * SEQ * 64;
    const __bf16* Kp  = Kb  + (size_t)bh * SEQ * 64;
    const __bf16* Vtp = Vtg + (size_t)bh * 64 * SEQ;   // [d][s]
    const float*  Mp  = mask + (size_t)b * SEQ * SEQ + (size_t)(q0 + l15) * SEQ;

    // V-stage thread mapping (each thread covers 2x16B rows of Vt)
    const int vd0 = t >> 3;            // t*8 /64      (0..31)
    const int vk0 = (t & 7) * 8;       // t*8 %64
    const int vd1 = vd0 + 32;

    // Q fragment (B-operand for S^T): lane q=l15, k=quad*8..
    bf16x8 qf[2];
#pragma unroll
    for (int ks = 0; ks < 2; ++ks)
        qf[ks] = *(const bf16x8*)(Qp + (size_t)(q0 + l15) * 64 + ks * 32 + quad * 8);

    // ---- prologue: prefetch tile 0 (V, mask, K) + compute sa(0) ----
    uint4 vst[2];
    vst[0] = *(const uint4*)(Vtp + (size_t)vd0 * SEQ + vk0);
    vst[1] = *(const uint4*)(Vtp + (size_t)vd1 * SEQ + vk0);
    float4 mreg[4];
#pragma unroll
    for (int nb = 0; nb < 4; ++nb)
        mreg[nb] = *(const float4*)(Mp + nb * 16 + quad * 4);
    bf16x8 kf0[4], kf1[4];
#pragma unroll
    for (int nb = 0; nb < 4; ++nb) {
        const __bf16* kp = Kp + (size_t)(nb * 16 + l15) * 64;
        kf0[nb] = *(const bf16x8*)(kp + quad * 8);
        kf1[nb] = *(const bf16x8*)(kp + 32 + quad * 8);
    }
    f32x4 sa[4];
#pragma unroll
    for (int nb = 0; nb < 4; ++nb) {
        f32x4 z = {};
        z = __builtin_amdgcn_mfma_f32_16x16x32_bf16(kf0[nb], qf[0], z, 0, 0, 0);
        z = __builtin_amdgcn_mfma_f32_16x16x32_bf16(kf1[nb], qf[1], z, 0, 0, 0);
        sa[nb] = z;
    }

    f32x4 oacc[4] = {};
    float mrun = -1e30f, lrun = 0.f;   // stats for q=l15 (replicated per quad)

    const int NT = SEQ / 64;
    for (int kt = 0; kt < NT; ++kt) {
        const int buf  = kt & 1;
        const int keyn = (kt + 1 < NT) ? (kt + 1) * 64 : 0;   // wrap: harmless

        // ---- commit V(kt) regs -> LDS dbuf ----
        *(uint4*)(&Vt[buf][vd0][vk0]) = vst[0];
        *(uint4*)(&Vt[buf][vd1][vk0]) = vst[1];

        __syncthreads();   // single barrier: Vt[buf] visible; in-flight ~empty

        // ---- prefetch V(kt+1) (lands at next iter's commit) ----
        vst[0] = *(const uint4*)(Vtp + (size_t)vd0 * SEQ + keyn + vk0);
        vst[1] = *(const uint4*)(Vtp + (size_t)vd1 * SEQ + keyn + vk0);

        // ---- masked scores from sa(kt) + mreg(kt) ----
        float s[4][4];
#pragma unroll
        for (int nb = 0; nb < 4; ++nb) {
            float4 mq = mreg[nb];
            s[nb][0] = sa[nb][0] * 0.125f * mq.x + (mq.x - 1.0f) * 10000.0f;
            s[nb][1] = sa[nb][1] * 0.125f * mq.y + (mq.y - 1.0f) * 10000.0f;
            s[nb][2] = sa[nb][2] * 0.125f * mq.z + (mq.z - 1.0f) * 10000.0f;
            s[nb][3] = sa[nb][3] * 0.125f * mq.w + (mq.w - 1.0f) * 10000.0f;
        }
        // ---- prefetch mask(kt+1) ----
#pragma unroll
        for (int nb = 0; nb < 4; ++nb)
            mreg[nb] = *(const float4*)(Mp + keyn + nb * 16 + quad * 4);

        // ---- softmax for q=l15: in-lane 16 + 2 cross-quad shfls ----
        float vmax = s[0][0];
#pragma unroll
        for (int nb = 0; nb < 4; ++nb)
#pragma unroll
            for (int r = 0; r < 4; ++r) vmax = fmaxf(vmax, s[nb][r]);
        vmax = fmaxf(vmax, __shfl_xor(vmax, 16));
        vmax = fmaxf(vmax, __shfl_xor(vmax, 32));
        float mnew  = fmaxf(mrun, vmax);
        float alpha = __expf(mrun - mnew);
        mrun = mnew;
        float psum = 0.f;
#pragma unroll
        for (int nb = 0; nb < 4; ++nb)
#pragma unroll
            for (int r = 0; r < 4; ++r) {
                float p = __expf(s[nb][r] - mnew);
                s[nb][r] = p;
                psum += p;
            }
        psum += __shfl_xor(psum, 16);
        psum += __shfl_xor(psum, 32);
        lrun = lrun * alpha + psum;

        // ---- P store (wave-private; lgkm ordering, no barrier) ----
#pragma unroll
        for (int nb = 0; nb < 4; ++nb) {
            __bf16 pk[4] = { (__bf16)s[nb][0], (__bf16)s[nb][1],
                             (__bf16)s[nb][2], (__bf16)s[nb][3] };
            *(uint2*)(&Ps[wave][l15][nb * 16 + quad * 4]) = *(uint2*)pk;
        }
        // ---- prefetch K(kt+1): latency covered by rescale+PV below ----
#pragma unroll
        for (int nb = 0; nb < 4; ++nb) {
            const __bf16* kp = Kp + (size_t)(keyn + nb * 16 + l15) * 64;
            kf0[nb] = *(const bf16x8*)(kp + quad * 8);
            kf1[nb] = *(const bf16x8*)(kp + 32 + quad * 8);
        }
        // ---- O rescale (alpha for q-rows quad*4+r via lane read) ----
        float arow_[4];
#pragma unroll
        for (int r = 0; r < 4; ++r)
            arow_[r] = __shfl(alpha, quad * 4 + r);
#pragma unroll
        for (int cb = 0; cb < 4; ++cb)
#pragma unroll
            for (int r = 0; r < 4; ++r)
                oacc[cb][r] *= arow_[r];
        // ---- O += P V from Vt[buf] ----
        bf16x8 pf[2];
#pragma unroll
        for (int ks = 0; ks < 2; ++ks)
            pf[ks] = *(const bf16x8*)(&Ps[wave][l15][ks * 32 + quad * 8]);
#pragma unroll
        for (int cb = 0; cb < 4; ++cb) {
#pragma unroll
            for (int ks = 0; ks < 2; ++ks) {
                bf16x8 vf = *(const bf16x8*)(&Vt[buf][cb * 16 + l15][ks * 32 + quad * 8]);
                oacc[cb] = __builtin_amdgcn_mfma_f32_16x16x32_bf16(pf[ks], vf, oacc[cb], 0, 0, 0);
            }
        }
        // ---- QK(kt+1) pipelined across the barrier ----
#pragma unroll
        for (int nb = 0; nb < 4; ++nb) {
            f32x4 z = {};
            z = __builtin_amdgcn_mfma_f32_16x16x32_bf16(kf0[nb], qf[0], z, 0, 0, 0);
            z = __builtin_amdgcn_mfma_f32_16x16x32_bf16(kf1[nb], qf[1], z, 0, 0, 0);
            sa[nb] = z;
        }
    }
    // epilogue: lrun for q-rows quad*4+r
    float lr[4];
#pragma unroll
    for (int r = 0; r < 4; ++r)
        lr[r] = __shfl(lrun, quad * 4 + r);
#pragma unroll
    for (int cb = 0; cb < 4; ++cb) {
#pragma unroll
        for (int r = 0; r < 4; ++r) {
            int qq = q0 + quad * 4 + r;
            float v = oacc[cb][r] / lr[r];
            Out[((size_t)(b * SEQ + qq)) * DMODEL + h * 64 + cb * 16 + l15] = (__bf16)v;
        }
    }
}

// ---------------------------------------------------------------------------
extern "C" void kernel_launch(void* const* d_in, const int* in_sizes, int n_in,
                              void* d_out, int out_size, void* d_ws, size_t ws_size,
                              hipStream_t stream)
{
    const float* src  = nullptr;  // 4194304
    const float* mask = nullptr;  // 8388608
    const float* Wqkv = nullptr;  // 3145728
    const float* bqkv = nullptr;  // 3072
    const float* Wout = nullptr;  // 1048576
    const float* bout = nullptr;  // 1024
    for (int i = 0; i < n_in; ++i) {
        switch (in_sizes[i]) {
            case 4194304: src  = (const float*)d_in[i]; break;
            case 8388608: mask = (const float*)d_in[i]; break;
            case 3145728: Wqkv = (const float*)d_in[i]; break;
            case 3072:    bqkv = (const float*)d_in[i]; break;
            case 1048576: Wout = (const float*)d_in[i]; break;
            case 1024:    bout = (const float*)d_in[i]; break;
        }
    }
    float* out = (float*)d_out;                  // [2,2048,1024] fp32

    const size_t NE = (size_t)2 * 16 * SEQ * 64; // 4M elems
    __bf16* Qb     = (__bf16*)d_ws;              // 4M
    __bf16* Kb     = Qb + NE;                    // 4M
    __bf16* Vb     = Kb + NE;                    // 4M (dead after transpose_v)
    __bf16* Vtg    = Vb + NE;                    // 4M  [bh][d][s]
    __bf16* Wqkv_t = Vtg + NE;                   // 3M  [3072][1024]
    __bf16* Wout_t = Wqkv_t + (size_t)3072 * 1024; // 1M [1024][1024]
    __bf16* Ao     = Vb;                         // alias: Vb dead by then

    transpose_f32_to_bf16<<<dim3(3072 / 32, 1024 / 32), 256, 0, stream>>>(
        Wqkv, Wqkv_t, 1024, 3072);
    transpose_f32_to_bf16<<<dim3(1024 / 32, 1024 / 32), 256, 0, stream>>>(
        Wout, Wout_t, 1024, 1024);

    gemm_kernel<true><<<dim3(3072 / 128, 4096 / 128), 256, 0, stream>>>(
        (const void*)src, Wqkv_t, bqkv, Qb, Kb, Vb, nullptr, 1024, 3072, 0);

    transpose_v<<<dim3(SEQ / 32, 2, 32), 256, 0, stream>>>(Vb, Vtg);

    attn_kernel<<<dim3(32, SEQ / 64), 256, 0, stream>>>(Qb, Kb, Vtg, mask, Ao);

    gemm_kernel<false><<<dim3(1024 / 128, 4096 / 128), 256, 0, stream>>>(
        (const void*)Ao, Wout_t, bout, nullptr, nullptr, nullptr, out, 1024, 1024, 1);
}